// Round 10
// baseline (616.548 us; speedup 1.0000x reference)
//
#include <hip/hip_runtime.h>
#include <hip/hip_cooperative_groups.h>

namespace cg = cooperative_groups;

#define N_NODES 50000
#define N_GRAPHS 128
#define HID 512

// Split-K geometry: Psum[128 x 512] = C[128 x K] * x[K x 512]
#define KSPAN   272                      // 17 k-steps of 16 per wave
#define NSTEP   17
#define KS2     48                       // part slices (one per k-group)
#define KSPLIT  (KS2 * 4)                // 192 wave-level k-splits
#define KPAD    (KSPAN * KSPLIT)         // 52224
#define NPANEL  (KPAD / 16)              // 3264

// Workspace layout (16B-aligned sections)
#define C8_OFF     0
#define C8_BYTES   ((size_t)N_GRAPHS * KPAD)                 // 6,684,672
#define PSUM_OFF   (C8_OFF + C8_BYTES)
#define PSUM_BYTES ((size_t)N_GRAPHS * HID * 4)              // 262,144
#define COUNTS_OFF (PSUM_OFF + PSUM_BYTES)
#define ZERO_BYTES (COUNTS_OFF + 512)                        // zero C8+Psum+counts
#define APACK_OFF  ZERO_BYTES
#define APACK_BYTES ((size_t)NPANEL * 4 * 64 * 16)           // 13,369,344
#define PART_OFF   (APACK_OFF + APACK_BYTES)
#define PART_BYTES ((size_t)KS2 * N_GRAPHS * HID * 4)        // 12,582,912

typedef __attribute__((ext_vector_type(8))) short bf16x8;
typedef __attribute__((ext_vector_type(16))) float f32x16;

// ---------------------------------------------------------------------------
// Build byte-packed counts C8[g][node] (row stride KPAD) + per-graph path
// counts via LDS histogram. (verified form)
// ---------------------------------------------------------------------------
__global__ __launch_bounds__(256)
void build_c_kernel(const int* __restrict__ w2, const int* __restrict__ w3,
                    const int* __restrict__ w4, const int* __restrict__ batch,
                    unsigned int* __restrict__ C32, int* __restrict__ counts) {
    __shared__ int hist[N_GRAPHS];
    const int t = threadIdx.x;
    if (t < N_GRAPHS) hist[t] = 0;
    __syncthreads();
    const int i = blockIdx.x * 256 + t;
    if (i < N_NODES) {
        const int a = w2[i];            // walk2[0][i] — path anchor
        const int g = batch[a];
        atomicAdd(&hist[g], 1);
        unsigned int* row = C32 + (size_t)g * (KPAD / 4);
        int nn[12];
        nn[0]  = a;
        nn[1]  = w2[N_NODES + i];
        nn[2]  = w2[2 * N_NODES + i];
        nn[3]  = w3[i];
        nn[4]  = w3[N_NODES + i];
        nn[5]  = w3[2 * N_NODES + i];
        nn[6]  = w3[3 * N_NODES + i];
        nn[7]  = w4[i];
        nn[8]  = w4[N_NODES + i];
        nn[9]  = w4[2 * N_NODES + i];
        nn[10] = w4[3 * N_NODES + i];
        nn[11] = w4[4 * N_NODES + i];
#pragma unroll
        for (int j = 0; j < 12; ++j) {
            const int nd = nn[j];
            atomicAdd(&row[nd >> 2], 1u << ((nd & 3) * 8));
        }
    }
    __syncthreads();
    if (t < N_GRAPHS) { const int hv = hist[t]; if (hv) atomicAdd(&counts[t], hv); }
}

__device__ inline unsigned pack_bf16(unsigned a, unsigned b) {
    // exact: u8 -> f32 -> truncate to bf16 (u8 mantissa fits in bf16)
    return (__builtin_bit_cast(unsigned, (float)a) >> 16) |
           (__builtin_bit_cast(unsigned, (float)b) & 0xFFFF0000u);
}

// ---------------------------------------------------------------------------
// Repack u8 counts into MFMA A-fragment order (coalesced loads in the GEMM).
// ---------------------------------------------------------------------------
__global__ __launch_bounds__(256)
void c8_to_apack_kernel(const unsigned char* __restrict__ C8,
                        uint4* __restrict__ Apack) {
    const int kp = blockIdx.x;           // 0..NPANEL-1
    const int t = threadIdx.x;
    const int mt = t >> 6;
    const int l = t & 63;
    const int row = mt * 32 + (l & 31);
    const int k0 = kp * 16 + 8 * (l >> 5);
    const uint2 b = *(const uint2*)(C8 + (size_t)row * KPAD + k0);
    uint4 o;
    o.x = pack_bf16(b.x & 0xFFu, (b.x >> 8) & 0xFFu);
    o.y = pack_bf16((b.x >> 16) & 0xFFu, b.x >> 24);
    o.z = pack_bf16(b.y & 0xFFu, (b.y >> 8) & 0xFFu);
    o.w = pack_bf16((b.y >> 16) & 0xFFu, b.y >> 24);
    Apack[(size_t)(kp * 4 + mt) * 64 + l] = o;
}

// ---------------------------------------------------------------------------
// Pool-GEMM phase pieces (round-8 verified pool_gemm7 body)
// ---------------------------------------------------------------------------
template <int GUARD>
__device__ inline void issue_b8(const float* __restrict__ xp, int krow,
                                unsigned (&u)[8]) {
#pragma unroll
    for (int j = 0; j < 8; ++j) {
        int k = krow + j;
        if (GUARD) k = min(k, N_NODES - 1);
        u[j] = __builtin_bit_cast(unsigned, xp[(size_t)k * HID]);
    }
}

__device__ inline f32x16 mfma_bf16(bf16x8 a, bf16x8 b, f32x16 c) {
    return __builtin_amdgcn_mfma_f32_32x32x16_bf16(a, b, c, 0, 0, 0);
}

__device__ inline unsigned bpack(unsigned u0, unsigned u1) {
    return __builtin_amdgcn_perm(u1, u0, 0x07060302u);
}

__device__ inline void step_mfma4(const unsigned (&u)[8], const uint4 (&a)[4],
                                  f32x16 (&acc)[4]) {
    unsigned d[4];
#pragma unroll
    for (int jj = 0; jj < 4; ++jj) d[jj] = bpack(u[2 * jj], u[2 * jj + 1]);
    const bf16x8 b0 = __builtin_bit_cast(bf16x8, make_uint4(d[0], d[1], d[2], d[3]));
#pragma unroll
    for (int mt = 0; mt < 4; ++mt)
        acc[mt] = mfma_bf16(__builtin_bit_cast(bf16x8, a[mt]), b0, acc[mt]);
}

template <int GUARD>
__device__ inline void run_k4(const float* __restrict__ xp,
                              const uint4* __restrict__ Apack,
                              int kbase, int h, int lane,
                              f32x16 (&acc)[4]) {
    unsigned bu[3][8];
    uint4 au[3][4];
    const int kp0 = kbase >> 4;
#pragma unroll
    for (int s = 0; s < 3; ++s) {
        issue_b8<GUARD>(xp, kbase + s * 16 + 8 * h, bu[s]);
#pragma unroll
        for (int mt = 0; mt < 4; ++mt)
            au[s][mt] = Apack[(size_t)((kp0 + s) * 4 + mt) * 64 + lane];
    }
#pragma unroll
    for (int s = 0; s < NSTEP; ++s) {
        const int slot = s % 3;
        step_mfma4(bu[slot], au[slot], acc);
        if (s + 3 < NSTEP) {
            issue_b8<GUARD>(xp, kbase + (s + 3) * 16 + 8 * h, bu[slot]);
#pragma unroll
            for (int mt = 0; mt < 4; ++mt)
                au[slot][mt] = Apack[(size_t)((kp0 + s + 3) * 4 + mt) * 64 + lane];
        }
    }
}

// Pool phase: wave computes ALL 128 graph rows x one 32-col slice.
// lb in [0,768): rn = lb & 15, ksg = lb >> 4.
template <int ATOMIC>
__device__ inline void pool_phase(float* __restrict__ smem, int lb, int t,
                                  const float* __restrict__ x,
                                  const uint4* __restrict__ Apack,
                                  float* __restrict__ dst) {
    float (*red)[16 * 64] = (float (*)[16 * 64])smem;   // 12 KB
    const int lane = t & 63;
    const int w = t >> 6;
    const int n = lane & 31;
    const int h = lane >> 5;
    const int rn = lb & 15;
    const int ksg = lb >> 4;
    const int ks = ksg * 4 + w;
    const int kbase = ks * KSPAN;

    f32x16 acc[4];
#pragma unroll
    for (int p = 0; p < 4; ++p)
#pragma unroll
        for (int r = 0; r < 16; ++r) acc[p][r] = 0.f;

    const float* xp = x + rn * 32 + n;

    if (kbase + KSPAN <= N_NODES) {
        run_k4<0>(xp, Apack, kbase, h, lane, acc);
    } else if (kbase < N_NODES) {
        run_k4<1>(xp, Apack, kbase, h, lane, acc);
    }

    float* outp = ATOMIC ? dst : dst + (size_t)ksg * (N_GRAPHS * HID);
#pragma unroll
    for (int p = 0; p < 4; ++p) {
        __syncthreads();
        if (w > 0) {
#pragma unroll
            for (int i = 0; i < 16; ++i)
                red[w - 1][i * 64 + lane] = acc[p][i];
        }
        __syncthreads();
        if (w == 0) {
#pragma unroll
            for (int i = 0; i < 16; ++i) {
                const float v = acc[p][i] + red[0][i * 64 + lane] +
                                red[1][i * 64 + lane] + red[2][i * 64 + lane];
                // C/D layout: col=lane&31, row=(i&3)+8*(i>>2)+4*h
                const int row = p * 32 + (i & 3) + 8 * (i >> 2) + 4 * h;
                const int col = rn * 32 + n;
                if (ATOMIC) atomicAdd(&outp[(size_t)row * HID + col], v);
                else        outp[(size_t)row * HID + col] = v;
            }
        }
    }
}

__device__ inline void reduce_phase(int lb, int t, const float* __restrict__ part,
                                    float* __restrict__ Psum) {
    const int id = lb * 256 + t;
    float s0 = 0.f, s1 = 0.f;
    for (int k = 0; k + 2 <= KS2; k += 2) {
        s0 += part[(size_t)k * (N_GRAPHS * HID) + id];
        s1 += part[(size_t)(k + 1) * (N_GRAPHS * HID) + id];
    }
    Psum[id] = s0 + s1;
}

// Layer phase (round-0 verified z-split form): lb<256 -> ct=lb&7, rt=(lb>>3)&7,
// ksb=lb>>6. Atomic-accumulates a 16x64 tile partial over a 128-k chunk.
__device__ inline void layer_phase(float* __restrict__ smem, int lb, int t,
                                   const float* __restrict__ A, int lda, int scaleA,
                                   const float* __restrict__ W,
                                   const float* __restrict__ bias,
                                   const int* __restrict__ counts,
                                   float* __restrict__ out) {
    if (lb >= 256) return;
    float (*Alds)[128] = (float (*)[128])smem;           // 8 KB
    const int ct = lb & 7, rt = (lb >> 3) & 7, ksb = lb >> 6;
    const int cc = ct * 64 + (t & 63);
    const int wv = t >> 6;
    const int k0 = ksb * 128;

    for (int idx = t; idx < 16 * 32; idx += 256) {
        const int rr = idx >> 5;
        const int kk = (idx & 31) * 4;
        const int row = rt * 16 + rr;
        float4 v = *(const float4*)&A[(size_t)row * lda + k0 + kk];
        if (scaleA) {
            const float inv = 1.f / (float)max(counts[row], 1);
            v.x *= inv; v.y *= inv; v.z *= inv; v.w *= inv;
        }
        *(float4*)&Alds[rr][kk] = v;
    }
    __syncthreads();

    const int r0 = rt * 16 + wv * 4;
    float a0 = 0.f, a1 = 0.f, a2 = 0.f, a3 = 0.f;
#pragma unroll 8
    for (int k = 0; k < 128; ++k) {
        const float wval = W[(size_t)(k0 + k) * HID + cc];
        a0 += Alds[wv * 4 + 0][k] * wval;
        a1 += Alds[wv * 4 + 1][k] * wval;
        a2 += Alds[wv * 4 + 2][k] * wval;
        a3 += Alds[wv * 4 + 3][k] * wval;
    }
    if (ksb == 0) {
        const float bc = bias[cc];
        a0 += (counts[r0 + 0] > 0 ? 12.f : 0.f) * bc;
        a1 += (counts[r0 + 1] > 0 ? 12.f : 0.f) * bc;
        a2 += (counts[r0 + 2] > 0 ? 12.f : 0.f) * bc;
        a3 += (counts[r0 + 3] > 0 ? 12.f : 0.f) * bc;
    }
    atomicAdd(&out[(size_t)(r0 + 0) * 1536 + cc], a0);
    atomicAdd(&out[(size_t)(r0 + 1) * 1536 + cc], a1);
    atomicAdd(&out[(size_t)(r0 + 2) * 1536 + cc], a2);
    atomicAdd(&out[(size_t)(r0 + 3) * 1536 + cc], a3);
    __syncthreads();   // protect smem before next phase reuses it
}

// ---------------------------------------------------------------------------
// Cooperative fused tail: pool -> reduce + zero(out) -> L0 -> L1 -> L2.
// grid = 768 = 256 CU x 3 blocks (guaranteed co-resident by launch bounds;
// runtime validates at launch). Replaces 6 dispatches + 1 memset with one.
// ---------------------------------------------------------------------------
__global__ __launch_bounds__(256, 3)
void fused_tail_kernel(const float* __restrict__ x, const uint4* __restrict__ Apack,
                       float* __restrict__ part, float* __restrict__ Psum,
                       const int* __restrict__ counts,
                       const float* __restrict__ W0, const float* __restrict__ b0,
                       const float* __restrict__ W1, const float* __restrict__ b1,
                       const float* __restrict__ W2, const float* __restrict__ b2,
                       float* __restrict__ out) {
    __shared__ float smem[3 * 16 * 64];      // 12 KB, unioned across phases
    cg::grid_group grid = cg::this_grid();
    const int lb = blockIdx.x;
    const int t = threadIdx.x;

    pool_phase<0>(smem, lb, t, x, Apack, part);
    grid.sync();

    if (lb < 256) reduce_phase(lb, t, part, Psum);
    else {
        for (int idx = (lb - 256) * 256 + t; idx < N_GRAPHS * 1536; idx += 512 * 256)
            out[idx] = 0.f;
    }
    grid.sync();

    layer_phase(smem, lb, t, Psum, HID, 1, W0, b0, counts, out);
    grid.sync();
    layer_phase(smem, lb, t, out, 1536, 0, W1, b1, counts, out + 512);
    grid.sync();
    layer_phase(smem, lb, t, out + 512, 1536, 0, W2, b2, counts, out + 1024);
}

// ---------------------------------------------------------------------------
// Fallback standalone kernels (round-8 path, verified)
// ---------------------------------------------------------------------------
template <int ATOMIC>
__global__ __launch_bounds__(256, 3)
void pool_gemm7_kernel(const float* __restrict__ x,
                       const uint4* __restrict__ Apack,
                       float* __restrict__ dst) {
    __shared__ float smem[3 * 16 * 64];
    pool_phase<ATOMIC>(smem, blockIdx.x + 16 * blockIdx.y, threadIdx.x, x, Apack, dst);
}

__global__ __launch_bounds__(256)
void reduce_part_kernel(const float* __restrict__ part, float* __restrict__ Psum) {
    reduce_phase(blockIdx.x, threadIdx.x, part, Psum);
}

__global__ __launch_bounds__(256)
void layer_gemm_kernel(const float* __restrict__ A, int lda, int scaleA,
                       const float* __restrict__ W,
                       const float* __restrict__ bias,
                       const int* __restrict__ counts,
                       float* __restrict__ out) {
    __shared__ float smem[16 * 128];
    layer_phase(smem, blockIdx.x + 8 * blockIdx.y + 64 * blockIdx.z, threadIdx.x,
                A, lda, scaleA, W, bias, counts, out);
}

extern "C" void kernel_launch(void* const* d_in, const int* in_sizes, int n_in,
                              void* d_out, int out_size, void* d_ws, size_t ws_size,
                              hipStream_t stream) {
    const float* x     = (const float*)d_in[0];
    const int*   w2    = (const int*)d_in[1];
    const int*   w3    = (const int*)d_in[2];
    const int*   w4    = (const int*)d_in[3];
    const int*   batch = (const int*)d_in[4];
    const float* W0    = (const float*)d_in[5];
    const float* b0    = (const float*)d_in[6];
    const float* W1    = (const float*)d_in[7];
    const float* b1    = (const float*)d_in[8];
    const float* W2    = (const float*)d_in[9];
    const float* b2    = (const float*)d_in[10];
    float* out = (float*)d_out;

    unsigned char* ws  = (unsigned char*)d_ws;
    unsigned int* C32  = (unsigned int*)(ws + C8_OFF);
    float* Psum        = (float*)(ws + PSUM_OFF);
    int* counts        = (int*)(ws + COUNTS_OFF);
    uint4* Apack       = (uint4*)(ws + APACK_OFF);
    float* part        = (float*)(ws + PART_OFF);
    const bool use_part = ws_size >= PART_OFF + PART_BYTES;

    static int coop_ok = -1;
    if (coop_ok < 0) {
        int dev = 0, v = 0;
        hipGetDevice(&dev);
        hipDeviceGetAttribute(&v, hipDeviceAttributeCooperativeLaunch, dev);
        coop_ok = v;
    }

    hipMemsetAsync(d_ws, 0, ZERO_BYTES, stream);      // C8 + Psum + counts

    build_c_kernel<<<(N_NODES + 255) / 256, 256, 0, stream>>>(w2, w3, w4, batch, C32, counts);
    c8_to_apack_kernel<<<NPANEL, 256, 0, stream>>>((const unsigned char*)C32, Apack);

    bool done = false;
    if (use_part && coop_ok) {
        void* args[] = {(void*)&x, (void*)&Apack, (void*)&part, (void*)&Psum,
                        (void*)&counts, (void*)&W0, (void*)&b0, (void*)&W1,
                        (void*)&b1, (void*)&W2, (void*)&b2, (void*)&out};
        hipError_t err = hipLaunchCooperativeKernel(
            reinterpret_cast<void*>(fused_tail_kernel), dim3(16 * KS2), dim3(256),
            args, 0, stream);
        done = (err == hipSuccess);
    }

    if (!done) {
        // round-8 verified multi-dispatch path
        hipMemsetAsync(d_out, 0, (size_t)out_size * 4, stream);
        if (use_part) {
            pool_gemm7_kernel<0><<<dim3(16, KS2), 256, 0, stream>>>(x, Apack, part);
            reduce_part_kernel<<<256, 256, 0, stream>>>(part, Psum);
        } else {
            pool_gemm7_kernel<1><<<dim3(16, KS2), 256, 0, stream>>>(x, Apack, Psum);
        }
        layer_gemm_kernel<<<dim3(8, 8, 4), 256, 0, stream>>>(Psum, HID, 1, W0, b0, counts, out);
        layer_gemm_kernel<<<dim3(8, 8, 4), 256, 0, stream>>>(out, 1536, 0, W1, b1, counts, out + 512);
        layer_gemm_kernel<<<dim3(8, 8, 4), 256, 0, stream>>>(out + 512, 1536, 0, W2, b2, counts, out + 1024);
    }
}

// Round 11
// 265.155 us; speedup vs baseline: 2.3252x; 2.3252x over previous
//
#include <hip/hip_runtime.h>

#define N_NODES 50000
#define N_GRAPHS 128
#define HID 512

// Split-K geometry: Psum[128 x 512] = C[128 x K] * x[K x 512]
#define KSPAN   272                      // 17 k-steps of 16 per wave
#define NSTEP   17
#define KS2     48                       // part slices (one per k-group); 8 XCD x 6
#define KSPLIT  (KS2 * 4)                // 192 wave-level k-splits
#define KPAD    (KSPAN * KSPLIT)         // 52224
#define NPANEL  (KPAD / 16)              // 3264

// Workspace layout (16B-aligned sections)
#define C8_OFF     0
#define C8_BYTES   ((size_t)N_GRAPHS * KPAD)                 // 6,684,672
#define PSUM_OFF   (C8_OFF + C8_BYTES)
#define PSUM_BYTES ((size_t)N_GRAPHS * HID * 4)              // 262,144
#define COUNTS_OFF (PSUM_OFF + PSUM_BYTES)
#define ZERO_BYTES (COUNTS_OFF + 512)                        // zero C8+Psum+counts
#define APACK_OFF  ZERO_BYTES
#define APACK_BYTES ((size_t)NPANEL * 4 * 64 * 16)           // 13,369,344
#define PART_OFF   (APACK_OFF + APACK_BYTES)
#define PART_BYTES ((size_t)KS2 * N_GRAPHS * HID * 4)        // 12,582,912

typedef __attribute__((ext_vector_type(8))) short bf16x8;
typedef __attribute__((ext_vector_type(16))) float f32x16;

// ---------------------------------------------------------------------------
// Build byte-packed counts C8[g][node] (row stride KPAD) + per-graph path
// counts via LDS histogram. Also zeroes d_out (replaces a memset dispatch;
// stream order guarantees it completes before layer_gemm's atomics).
// ---------------------------------------------------------------------------
__global__ __launch_bounds__(256)
void build_c_kernel(const int* __restrict__ w2, const int* __restrict__ w3,
                    const int* __restrict__ w4, const int* __restrict__ batch,
                    unsigned int* __restrict__ C32, int* __restrict__ counts,
                    float* __restrict__ outz, int outn) {
    __shared__ int hist[N_GRAPHS];
    const int t = threadIdx.x;
    if (t < N_GRAPHS) hist[t] = 0;
    __syncthreads();
    const int i = blockIdx.x * 256 + t;
    // grid-stride zero of the output buffer (196 blocks x 256 threads)
    for (int z = i; z < outn; z += gridDim.x * 256) outz[z] = 0.f;
    if (i < N_NODES) {
        const int a = w2[i];            // walk2[0][i] — path anchor
        const int g = batch[a];
        atomicAdd(&hist[g], 1);
        unsigned int* row = C32 + (size_t)g * (KPAD / 4);
        int nn[12];
        nn[0]  = a;
        nn[1]  = w2[N_NODES + i];
        nn[2]  = w2[2 * N_NODES + i];
        nn[3]  = w3[i];
        nn[4]  = w3[N_NODES + i];
        nn[5]  = w3[2 * N_NODES + i];
        nn[6]  = w3[3 * N_NODES + i];
        nn[7]  = w4[i];
        nn[8]  = w4[N_NODES + i];
        nn[9]  = w4[2 * N_NODES + i];
        nn[10] = w4[3 * N_NODES + i];
        nn[11] = w4[4 * N_NODES + i];
#pragma unroll
        for (int j = 0; j < 12; ++j) {
            const int nd = nn[j];
            atomicAdd(&row[nd >> 2], 1u << ((nd & 3) * 8));
        }
    }
    __syncthreads();
    if (t < N_GRAPHS) { const int hv = hist[t]; if (hv) atomicAdd(&counts[t], hv); }
}

__device__ inline unsigned pack_bf16(unsigned a, unsigned b) {
    // exact: u8 -> f32 -> truncate to bf16 (u8 mantissa fits in bf16)
    return (__builtin_bit_cast(unsigned, (float)a) >> 16) |
           (__builtin_bit_cast(unsigned, (float)b) & 0xFFFF0000u);
}

// ---------------------------------------------------------------------------
// Repack u8 counts into MFMA A-fragment order (coalesced loads in the GEMM).
// ---------------------------------------------------------------------------
__global__ __launch_bounds__(256)
void c8_to_apack_kernel(const unsigned char* __restrict__ C8,
                        uint4* __restrict__ Apack) {
    const int kp = blockIdx.x;           // 0..NPANEL-1
    const int t = threadIdx.x;
    const int mt = t >> 6;
    const int l = t & 63;
    const int row = mt * 32 + (l & 31);
    const int k0 = kp * 16 + 8 * (l >> 5);
    const uint2 b = *(const uint2*)(C8 + (size_t)row * KPAD + k0);
    uint4 o;
    o.x = pack_bf16(b.x & 0xFFu, (b.x >> 8) & 0xFFu);
    o.y = pack_bf16((b.x >> 16) & 0xFFu, b.x >> 24);
    o.z = pack_bf16(b.y & 0xFFu, (b.y >> 8) & 0xFFu);
    o.w = pack_bf16((b.y >> 16) & 0xFFu, b.y >> 24);
    Apack[(size_t)(kp * 4 + mt) * 64 + l] = o;
}

// ---------------------------------------------------------------------------
// B-load: 8 global dwords per step per lane (one 32-col slice), straight into
// VGPRs in MFMA B-fragment order (k = 8h+j, n = lane&31). GUARD clamps k for
// the tail split (A is zero there, so clamped values contribute nothing).
// ---------------------------------------------------------------------------
template <int GUARD>
__device__ inline void issue_b8(const float* __restrict__ xp, int krow,
                                unsigned (&u)[8]) {
#pragma unroll
    for (int j = 0; j < 8; ++j) {
        int k = krow + j;
        if (GUARD) k = min(k, N_NODES - 1);
        u[j] = __builtin_bit_cast(unsigned, xp[(size_t)k * HID]);
    }
}

__device__ inline f32x16 mfma_bf16(bf16x8 a, bf16x8 b, f32x16 c) {
    return __builtin_amdgcn_mfma_f32_32x32x16_bf16(a, b, c, 0, 0, 0);
}

// one v_perm per dword: [b0,b1]=u0.bytes[2,3], [b2,b3]=u1.bytes[2,3]
__device__ inline unsigned bpack(unsigned u0, unsigned u1) {
    return __builtin_amdgcn_perm(u1, u0, 0x07060302u);
}

// One k-step: 4 MFMAs (four 32-row tiles = all 128 graphs) sharing one
// B fragment built from 8 x-dwords via 4 v_perm.
__device__ inline void step_mfma4(const unsigned (&u)[8], const uint4 (&a)[4],
                                  f32x16 (&acc)[4]) {
    unsigned d[4];
#pragma unroll
    for (int jj = 0; jj < 4; ++jj) d[jj] = bpack(u[2 * jj], u[2 * jj + 1]);
    const bf16x8 b0 = __builtin_bit_cast(bf16x8, make_uint4(d[0], d[1], d[2], d[3]));
#pragma unroll
    for (int mt = 0; mt < 4; ++mt)
        acc[mt] = mfma_bf16(__builtin_bit_cast(bf16x8, a[mt]), b0, acc[mt]);
}

// 3-deep register software pipeline over NSTEP k-steps: no barriers, no LDS
// staging. A-loads are fully-coalesced 16B bursts from Apack.
template <int GUARD>
__device__ inline void run_k4(const float* __restrict__ xp,
                              const uint4* __restrict__ Apack,
                              int kbase, int h, int lane,
                              f32x16 (&acc)[4]) {
    unsigned bu[3][8];
    uint4 au[3][4];
    const int kp0 = kbase >> 4;
#pragma unroll
    for (int s = 0; s < 3; ++s) {
        issue_b8<GUARD>(xp, kbase + s * 16 + 8 * h, bu[s]);
#pragma unroll
        for (int mt = 0; mt < 4; ++mt)
            au[s][mt] = Apack[(size_t)((kp0 + s) * 4 + mt) * 64 + lane];
    }
#pragma unroll
    for (int s = 0; s < NSTEP; ++s) {
        const int slot = s % 3;
        step_mfma4(bu[slot], au[slot], acc);
        if (s + 3 < NSTEP) {
            issue_b8<GUARD>(xp, kbase + (s + 3) * 16 + 8 * h, bu[slot]);
#pragma unroll
            for (int mt = 0; mt < 4; ++mt)
                au[slot][mt] = Apack[(size_t)((kp0 + s + 3) * 4 + mt) * 64 + lane];
        }
    }
}

// ---------------------------------------------------------------------------
// Barrier-free-K split-K MFMA GEMM. grid=(16, KS2) -> 768 blocks, block=256.
// Each wave computes ALL 128 graph rows x a 32-col slice.
// XCD-locality remap: HW assigns block lb to XCD lb&7 (round-robin). We give
// each XCD a contiguous set of ksg's and keep the 16 rn-blocks of one ksg
// dispatch-adjacent ON THE SAME XCD:
//   xcd = lb&7, idx = lb>>3 (0..95), rn = idx&15, ksg = xcd*6 + (idx>>4).
// Effect: the 2.2 MB x-row-span of a ksg is fetched into ONE L2 (not 8),
// cutting the ~8x L3-side duplication that bounds the current kernel; the
// 278 KB Apack slice per ksg is L2-resident. Pure index permutation —
// arithmetic identical.
// ---------------------------------------------------------------------------
template <int ATOMIC>
__global__ __launch_bounds__(256, 3)
void pool_gemm7_kernel(const float* __restrict__ x,
                       const uint4* __restrict__ Apack,
                       float* __restrict__ dst) {
    __shared__ float red[3][16 * 64];        // 12 KB
    const int t = threadIdx.x;
    const int lane = t & 63;
    const int w = t >> 6;
    const int n = lane & 31;
    const int h = lane >> 5;

    const int lb = blockIdx.x + 16 * blockIdx.y;   // 0..767 (dispatch order)
    const int xcd = lb & 7;
    const int idx = lb >> 3;                       // 0..95
    const int rn = idx & 15;                       // 32-col slice
    const int ksg = xcd * (KS2 / 8) + (idx >> 4);  // 0..47
    const int ks = ksg * 4 + w;
    const int kbase = ks * KSPAN;

    f32x16 acc[4];
#pragma unroll
    for (int p = 0; p < 4; ++p)
#pragma unroll
        for (int r = 0; r < 16; ++r) acc[p][r] = 0.f;

    const float* xp = x + rn * 32 + n;       // column base for this lane

    if (kbase + KSPAN <= N_NODES) {
        run_k4<0>(xp, Apack, kbase, h, lane, acc);
    } else if (kbase < N_NODES) {
        run_k4<1>(xp, Apack, kbase, h, lane, acc);
    }
    // fully-OOB waves: acc stays 0, still join the barriers below

    float* outp = ATOMIC ? dst : dst + (size_t)ksg * (N_GRAPHS * HID);
#pragma unroll
    for (int p = 0; p < 4; ++p) {
        __syncthreads();
        if (w > 0) {
#pragma unroll
            for (int i = 0; i < 16; ++i)
                red[w - 1][i * 64 + lane] = acc[p][i];
        }
        __syncthreads();
        if (w == 0) {
#pragma unroll
            for (int i = 0; i < 16; ++i) {
                const float v = acc[p][i] + red[0][i * 64 + lane] +
                                red[1][i * 64 + lane] + red[2][i * 64 + lane];
                // C/D layout: col=lane&31, row=(i&3)+8*(i>>2)+4*h
                const int row = p * 32 + (i & 3) + 8 * (i >> 2) + 4 * h;
                const int col = rn * 32 + n;
                if (ATOMIC) atomicAdd(&outp[(size_t)row * HID + col], v);
                else        outp[(size_t)row * HID + col] = v;
            }
        }
    }
}

// ---------------------------------------------------------------------------
// Psum = sum over KS2 partials (coalesced streams)
// ---------------------------------------------------------------------------
__global__ __launch_bounds__(256)
void reduce_part_kernel(const float* __restrict__ part, float* __restrict__ Psum) {
    const int id = blockIdx.x * 256 + threadIdx.x;
    float s0 = 0.f, s1 = 0.f;
    for (int k = 0; k + 2 <= KS2; k += 2) {
        s0 += part[(size_t)k * (N_GRAPHS * HID) + id];
        s1 += part[(size_t)(k + 1) * (N_GRAPHS * HID) + id];
    }
    Psum[id] = s0 + s1;
}

// ---------------------------------------------------------------------------
// out[r][c] += sum_k A[r][k] * W[k][c]  (+ 12*mask(r)*bias[c] on k-chunk 0)
// (round-0 verified form: z-split over 4 k-chunks, atomics into zeroed out)
// ---------------------------------------------------------------------------
__global__ __launch_bounds__(256)
void layer_gemm_kernel(const float* __restrict__ A, int lda, int scaleA,
                       const float* __restrict__ W,
                       const float* __restrict__ bias,
                       const int* __restrict__ counts,
                       float* __restrict__ out) {
    __shared__ float Alds[16][128];
    const int ct = blockIdx.x, rt = blockIdx.y, ksb = blockIdx.z;
    const int t = threadIdx.x;
    const int cc = ct * 64 + (t & 63);
    const int wv = t >> 6;
    const int k0 = ksb * 128;

    for (int idx = t; idx < 16 * 32; idx += 256) {
        const int rr = idx >> 5;
        const int kk = (idx & 31) * 4;
        const int row = rt * 16 + rr;
        float4 v = *(const float4*)&A[(size_t)row * lda + k0 + kk];
        if (scaleA) {
            const float inv = 1.f / (float)max(counts[row], 1);
            v.x *= inv; v.y *= inv; v.z *= inv; v.w *= inv;
        }
        *(float4*)&Alds[rr][kk] = v;
    }
    __syncthreads();

    const int r0 = rt * 16 + wv * 4;
    float a0 = 0.f, a1 = 0.f, a2 = 0.f, a3 = 0.f;
#pragma unroll 8
    for (int k = 0; k < 128; ++k) {
        const float wval = W[(size_t)(k0 + k) * HID + cc];
        a0 += Alds[wv * 4 + 0][k] * wval;
        a1 += Alds[wv * 4 + 1][k] * wval;
        a2 += Alds[wv * 4 + 2][k] * wval;
        a3 += Alds[wv * 4 + 3][k] * wval;
    }
    if (ksb == 0) {
        const float bc = bias[cc];
        a0 += (counts[r0 + 0] > 0 ? 12.f : 0.f) * bc;
        a1 += (counts[r0 + 1] > 0 ? 12.f : 0.f) * bc;
        a2 += (counts[r0 + 2] > 0 ? 12.f : 0.f) * bc;
        a3 += (counts[r0 + 3] > 0 ? 12.f : 0.f) * bc;
    }
    atomicAdd(&out[(size_t)(r0 + 0) * 1536 + cc], a0);
    atomicAdd(&out[(size_t)(r0 + 1) * 1536 + cc], a1);
    atomicAdd(&out[(size_t)(r0 + 2) * 1536 + cc], a2);
    atomicAdd(&out[(size_t)(r0 + 3) * 1536 + cc], a3);
}

extern "C" void kernel_launch(void* const* d_in, const int* in_sizes, int n_in,
                              void* d_out, int out_size, void* d_ws, size_t ws_size,
                              hipStream_t stream) {
    const float* x     = (const float*)d_in[0];
    const int*   w2    = (const int*)d_in[1];
    const int*   w3    = (const int*)d_in[2];
    const int*   w4    = (const int*)d_in[3];
    const int*   batch = (const int*)d_in[4];
    const float* W0    = (const float*)d_in[5];
    const float* b0    = (const float*)d_in[6];
    const float* W1    = (const float*)d_in[7];
    const float* b1    = (const float*)d_in[8];
    const float* W2    = (const float*)d_in[9];
    const float* b2    = (const float*)d_in[10];
    float* out = (float*)d_out;

    unsigned char* ws  = (unsigned char*)d_ws;
    unsigned int* C32  = (unsigned int*)(ws + C8_OFF);
    float* Psum        = (float*)(ws + PSUM_OFF);
    int* counts        = (int*)(ws + COUNTS_OFF);
    uint4* Apack       = (uint4*)(ws + APACK_OFF);
    float* part        = (float*)(ws + PART_OFF);
    const bool use_part = ws_size >= PART_OFF + PART_BYTES;

    hipMemsetAsync(d_ws, 0, ZERO_BYTES, stream);      // C8 + Psum + counts

    // build_c also zeroes d_out (saves the second memset dispatch)
    build_c_kernel<<<(N_NODES + 255) / 256, 256, 0, stream>>>(
        w2, w3, w4, batch, C32, counts, out, out_size);
    c8_to_apack_kernel<<<NPANEL, 256, 0, stream>>>((const unsigned char*)C32, Apack);

    if (use_part) {
        pool_gemm7_kernel<0><<<dim3(16, KS2), 256, 0, stream>>>(x, Apack, part);
        reduce_part_kernel<<<256, 256, 0, stream>>>(part, Psum);
    } else {
        pool_gemm7_kernel<1><<<dim3(16, KS2), 256, 0, stream>>>(x, Apack, Psum);
    }

    layer_gemm_kernel<<<dim3(8, 8, 4), 256, 0, stream>>>(Psum, HID, 1, W0, b0, counts, out);
    layer_gemm_kernel<<<dim3(8, 8, 4), 256, 0, stream>>>(out, 1536, 0, W1, b1, counts, out + 512);
    layer_gemm_kernel<<<dim3(8, 8, 4), 256, 0, stream>>>(out + 512, 1536, 0, W2, b2, counts, out + 1024);
}